// Round 1
// baseline (227.647 us; speedup 1.0000x reference)
//
#include <hip/hip_runtime.h>
#include <math.h>

// Problem constants
#define BB 16
#define NN 16384
#define DD 256
#define KK 32
#define RG 32            // rows per LDS group
#define XSTRIDE 260      // padded row stride (floats) for x / W tiles: bank-conflict-free
#define ASTRIDE 36       // padded row stride for a tile

// Fused kernel: per (b, chunk) block computes logits -> softmax -> partial VLAD accumulation.
// 256 threads. LDS ~71KB -> 2 blocks/CU, 8 waves/CU.
__launch_bounds__(256, 2)
__global__ void netvlad_k1(const float* __restrict__ x,
                           const float* __restrict__ W,
                           const float* __restrict__ bias,
                           float* __restrict__ vpart,
                           float* __restrict__ apart,
                           int CHnum) {
    __shared__ float Wl[KK][XSTRIDE];   // 33.3 KB
    __shared__ float xl[RG][XSTRIDE];   // 33.3 KB
    __shared__ float al[RG][ASTRIDE];   // 4.6 KB
    __shared__ float bl[KK];

    const int t  = threadIdx.x;
    const int bi = blockIdx.x / CHnum;
    const int ch = blockIdx.x % CHnum;
    const int NC = NN / CHnum;          // rows per chunk
    const int NG = NC / RG;             // groups per chunk

    const float* xb = x + ((size_t)bi * NN + (size_t)ch * NC) * DD;

    // Load W (+bias) into LDS, padded layout. 2048 float4s, coalesced.
    for (int i = 0; i < 8; i++) {
        int f = i * 256 + t;            // float4 index in [0,2048)
        int k = f >> 6, c4 = f & 63;
        *(float4*)&Wl[k][c4 * 4] = ((const float4*)W)[f];
    }
    if (t < KK) bl[t] = bias[t];

    float vacc[KK];
#pragma unroll
    for (int k = 0; k < KK; k++) vacc[k] = 0.0f;
    float asum[4] = {0.f, 0.f, 0.f, 0.f};

    const int r8 = t >> 3;              // phase-A row slot (0..31)
    const int kq = t & 7;               // phase-A k group (k in {kq+8j})

    __syncthreads();

    for (int g = 0; g < NG; g++) {
        // ---- stage x rows [g*RG, g*RG+RG) : 32KB coalesced ----
        const float* xg = xb + (size_t)g * RG * DD;
        for (int i = 0; i < 8; i++) {
            int f = i * 256 + t;        // float4 index in [0,2048)
            int r = f >> 6, c4 = f & 63;
            *(float4*)&xl[r][c4 * 4] = ((const float4*)xg)[f];
        }
        __syncthreads();

        // ---- phase A: logits for row r8, k = kq + 8j ----
        float lg0 = bl[kq], lg1 = bl[kq + 8], lg2 = bl[kq + 16], lg3 = bl[kq + 24];
#pragma unroll 4
        for (int d4 = 0; d4 < 64; d4++) {
            float4 xv = *(float4*)&xl[r8][d4 * 4];
            float4 w0 = *(float4*)&Wl[kq][d4 * 4];
            float4 w1 = *(float4*)&Wl[kq + 8][d4 * 4];
            float4 w2 = *(float4*)&Wl[kq + 16][d4 * 4];
            float4 w3 = *(float4*)&Wl[kq + 24][d4 * 4];
            lg0 += xv.x * w0.x + xv.y * w0.y + xv.z * w0.z + xv.w * w0.w;
            lg1 += xv.x * w1.x + xv.y * w1.y + xv.z * w1.z + xv.w * w1.w;
            lg2 += xv.x * w2.x + xv.y * w2.y + xv.z * w2.z + xv.w * w2.w;
            lg3 += xv.x * w3.x + xv.y * w3.y + xv.z * w3.z + xv.w * w3.w;
        }

        // ---- softmax over k (8 lanes share row r8; xor masks 1,2,4 stay in group) ----
        float m = fmaxf(fmaxf(lg0, lg1), fmaxf(lg2, lg3));
        m = fmaxf(m, __shfl_xor(m, 1));
        m = fmaxf(m, __shfl_xor(m, 2));
        m = fmaxf(m, __shfl_xor(m, 4));
        float p0 = __expf(lg0 - m), p1 = __expf(lg1 - m);
        float p2 = __expf(lg2 - m), p3 = __expf(lg3 - m);
        float ss = p0 + p1 + p2 + p3;
        ss += __shfl_xor(ss, 1);
        ss += __shfl_xor(ss, 2);
        ss += __shfl_xor(ss, 4);
        float inv = 1.0f / ss;
        float a0 = p0 * inv, a1 = p1 * inv, a2 = p2 * inv, a3 = p3 * inv;
        al[r8][kq]      = a0;  asum[0] += a0;
        al[r8][kq + 8]  = a1;  asum[1] += a1;
        al[r8][kq + 16] = a2;  asum[2] += a2;
        al[r8][kq + 24] = a3;  asum[3] += a3;
        __syncthreads();

        // ---- phase B: vacc[k] += a[n][k] * x[n][d=t] ----
#pragma unroll 2
        for (int n = 0; n < RG; n++) {
            float xv = xl[n][t];
            float4 q0 = *(float4*)&al[n][0];
            float4 q1 = *(float4*)&al[n][4];
            float4 q2 = *(float4*)&al[n][8];
            float4 q3 = *(float4*)&al[n][12];
            float4 q4 = *(float4*)&al[n][16];
            float4 q5 = *(float4*)&al[n][20];
            float4 q6 = *(float4*)&al[n][24];
            float4 q7 = *(float4*)&al[n][28];
            vacc[0]  += q0.x * xv; vacc[1]  += q0.y * xv; vacc[2]  += q0.z * xv; vacc[3]  += q0.w * xv;
            vacc[4]  += q1.x * xv; vacc[5]  += q1.y * xv; vacc[6]  += q1.z * xv; vacc[7]  += q1.w * xv;
            vacc[8]  += q2.x * xv; vacc[9]  += q2.y * xv; vacc[10] += q2.z * xv; vacc[11] += q2.w * xv;
            vacc[12] += q3.x * xv; vacc[13] += q3.y * xv; vacc[14] += q3.z * xv; vacc[15] += q3.w * xv;
            vacc[16] += q4.x * xv; vacc[17] += q4.y * xv; vacc[18] += q4.z * xv; vacc[19] += q4.w * xv;
            vacc[20] += q5.x * xv; vacc[21] += q5.y * xv; vacc[22] += q5.z * xv; vacc[23] += q5.w * xv;
            vacc[24] += q6.x * xv; vacc[25] += q6.y * xv; vacc[26] += q6.z * xv; vacc[27] += q6.w * xv;
            vacc[28] += q7.x * xv; vacc[29] += q7.y * xv; vacc[30] += q7.z * xv; vacc[31] += q7.w * xv;
        }
        __syncthreads();   // protect xl/al before next stage
    }

    // ---- a_sum partial: reduce asum across row slots via al ----
    al[r8][kq]      = asum[0];
    al[r8][kq + 8]  = asum[1];
    al[r8][kq + 16] = asum[2];
    al[r8][kq + 24] = asum[3];
    __syncthreads();
    if (t < KK) {
        float s = 0.0f;
        for (int r = 0; r < RG; r++) s += al[r][t];
        apart[((size_t)bi * CHnum + ch) * KK + t] = s;
    }

    // ---- write v partial (coalesced) ----
    float* vp = vpart + (((size_t)bi * CHnum + ch) * KK) * DD;
#pragma unroll
    for (int k = 0; k < KK; k++) vp[(size_t)k * DD + t] = vacc[k];
}

// Reduce partials, subtract a_sum * k_mean, intra-normalize, global-normalize (= /sqrt(K)).
__global__ void netvlad_k2(const float* __restrict__ vpart,
                           const float* __restrict__ apart,
                           const float* __restrict__ kmean,
                           float* __restrict__ out,
                           int CHnum) {
    const int bi = blockIdx.x / KK;
    const int k  = blockIdx.x % KK;
    const int t  = threadIdx.x;   // d

    float v = 0.0f;
    for (int ch = 0; ch < CHnum; ch++)
        v += vpart[(((size_t)bi * CHnum + ch) * KK + k) * DD + t];

    float asum = 0.0f;
    for (int ch = 0; ch < CHnum; ch++)
        asum += apart[((size_t)bi * CHnum + ch) * KK + k];

    v -= asum * kmean[(size_t)k * DD + t];

    // block reduce sum of squares over 256 threads
    float sq = v * v;
    sq += __shfl_xor(sq, 1);  sq += __shfl_xor(sq, 2);  sq += __shfl_xor(sq, 4);
    sq += __shfl_xor(sq, 8);  sq += __shfl_xor(sq, 16); sq += __shfl_xor(sq, 32);
    __shared__ float red[4];
    if ((t & 63) == 0) red[t >> 6] = sq;
    __syncthreads();
    float tot = red[0] + red[1] + red[2] + red[3];

    const float EPS = 1e-12f;
    float invn = 1.0f / fmaxf(sqrtf(tot), EPS);
    // After intra-normalization every cluster has unit norm -> global norm = sqrt(K).
    const float invK = 0.1767766952966369f;  // 1/sqrt(32)
    out[((size_t)bi * KK + k) * DD + t] = v * invn * invK;
}

extern "C" void kernel_launch(void* const* d_in, const int* in_sizes, int n_in,
                              void* d_out, int out_size, void* d_ws, size_t ws_size,
                              hipStream_t stream) {
    const float* x     = (const float*)d_in[0];
    const float* W     = (const float*)d_in[1];
    const float* bias  = (const float*)d_in[2];
    const float* kmean = (const float*)d_in[3];
    float* out = (float*)d_out;
    float* ws  = (float*)d_ws;

    // Per-chunk ws need: B*K*(D+1) floats = 526,336 bytes. Prefer CH=32 (512 blocks, 2/CU).
    int CH = 32;
    while (CH > 1 && (size_t)CH * 526336ULL > ws_size) CH >>= 1;

    float* vpart = ws;
    float* apart = ws + (size_t)BB * CH * KK * DD;

    hipLaunchKernelGGL(netvlad_k1, dim3(BB * CH), dim3(256), 0, stream,
                       x, W, bias, vpart, apart, CH);
    hipLaunchKernelGGL(netvlad_k2, dim3(BB * KK), dim3(256), 0, stream,
                       vpart, apart, kmean, out, CH);
}

// Round 2
// 155.256 us; speedup vs baseline: 1.4663x; 1.4663x over previous
//
#include <hip/hip_runtime.h>
#include <math.h>

// Problem constants
#define BB 16
#define NN 16384
#define DD 256
#define KK 32
#define RG 32            // rows per LDS group
#define ASTRIDE 36       // padded row stride for logits/a tile

typedef short bf16x8 __attribute__((ext_vector_type(8)));
typedef float f32x4 __attribute__((ext_vector_type(4)));

__device__ inline ushort f2bf(float f) {
    union { float f; unsigned u; } v; v.f = f;
    unsigned r = v.u + 0x7fffu + ((v.u >> 16) & 1u);   // RNE
    return (ushort)(r >> 16);
}
__device__ inline float bf2f(ushort h) {
    union { unsigned u; float f; } v; v.u = ((unsigned)h) << 16;
    return v.f;
}

// Fused: stage x as bf16 (swizzled LDS) -> MFMA logits -> fp32 softmax -> VALU aggregation.
// 256 threads = 4 waves. LDS ~21KB. Target ~4 blocks/CU.
__launch_bounds__(256, 4)
__global__ void netvlad_k1(const float* __restrict__ x,
                           const float* __restrict__ W,
                           const float* __restrict__ bias,
                           float* __restrict__ vpart,
                           float* __restrict__ apart,
                           int CHnum) {
    __shared__ ushort xh[RG * DD];      // bf16 x tile, XOR-swizzled rows, 16KB
    __shared__ float  al[RG][ASTRIDE];  // logits -> a buffer, 4.6KB

    const int t    = threadIdx.x;
    const int lane = t & 63;
    const int w    = t >> 6;            // wave 0..3
    const int bi   = blockIdx.x / CHnum;
    const int ch   = blockIdx.x % CHnum;
    const int NC   = NN / CHnum;
    const int NG   = NC / RG;

    const float* xb = x + ((size_t)bi * NN + (size_t)ch * NC) * DD;

    // ---- per-wave GEMM1 tile assignment: kc-tile = w&1, n-tile = w>>1 ----
    const int kct = (w & 1) * 16;
    const int nt  = (w >> 1) * 16;
    const int lr  = lane & 15;          // MFMA row/col index
    const int lg4 = lane >> 4;          // MFMA k-block / C row-block

    // Preload this wave's W fragments (A-operand, bf16) into registers.
    // A-frag: lane holds A[row=lr][k = lg4*8 + j], j=0..7; k = d.
    bf16x8 wf[8];
    for (int ks = 0; ks < 8; ks++) {
        const float* wp = W + (size_t)(kct + lr) * DD + ks * 32 + lg4 * 8;
        float4 w0 = *(const float4*)wp;
        float4 w1 = *(const float4*)(wp + 4);
        bf16x8 f;
        f[0] = (short)f2bf(w0.x); f[1] = (short)f2bf(w0.y);
        f[2] = (short)f2bf(w0.z); f[3] = (short)f2bf(w0.w);
        f[4] = (short)f2bf(w1.x); f[5] = (short)f2bf(w1.y);
        f[6] = (short)f2bf(w1.z); f[7] = (short)f2bf(w1.w);
        wf[ks] = f;
    }
    // bias for C-init: C reg r <-> kc = kct + lg4*4 + r
    float cb[4];
    for (int r = 0; r < 4; r++) cb[r] = bias[kct + lg4 * 4 + r];

    float vacc[KK];
#pragma unroll
    for (int k = 0; k < KK; k++) vacc[k] = 0.0f;
    float asum[4] = {0.f, 0.f, 0.f, 0.f};
    const int r8 = t >> 3;              // softmax row slot (0..31)
    const int kq = t & 7;               // softmax k group

    for (int g = 0; g < NG; g++) {
        // ---- stage x rows -> bf16 LDS (swizzled: ushort idx ^= (row&7)<<3) ----
        const float* xg = xb + (size_t)g * RG * DD;
        for (int i = 0; i < 8; i++) {
            int f = i * 256 + t;        // float4 index in [0,2048)
            int r = f >> 6, c4 = f & 63;
            float4 xv = ((const float4*)xg)[f];
            short4 s;
            s.x = (short)f2bf(xv.x); s.y = (short)f2bf(xv.y);
            s.z = (short)f2bf(xv.z); s.w = (short)f2bf(xv.w);
            int idx = (r * DD + c4 * 4) ^ ((r & 7) << 3);
            *(short4*)&xh[idx] = s;
        }
        __syncthreads();

        // ---- GEMM1^T via MFMA: Lt[kc][n] = sum_d W[kc][d]*x[n][d] + b ----
        {
            f32x4 c; c[0] = cb[0]; c[1] = cb[1]; c[2] = cb[2]; c[3] = cb[3];
            const int n = nt + lr;
#pragma unroll
            for (int ks = 0; ks < 8; ks++) {
                int d0  = ks * 32 + lg4 * 8;
                int idx = (n * DD + d0) ^ ((n & 7) << 3);
                bf16x8 bfr = *(const bf16x8*)&xh[idx];
                c = __builtin_amdgcn_mfma_f32_16x16x32_bf16(wf[ks], bfr, c, 0, 0, 0);
            }
            // C layout: col = lr -> n ; row = lg4*4 + r -> kc
#pragma unroll
            for (int r = 0; r < 4; r++) al[n][kct + lg4 * 4 + r] = c[r];
        }
        __syncthreads();

        // ---- softmax over kc (fp32, 8 lanes per row) ----
        {
            float lg0 = al[r8][kq], lg1 = al[r8][kq + 8];
            float lg2 = al[r8][kq + 16], lg3 = al[r8][kq + 24];
            float m = fmaxf(fmaxf(lg0, lg1), fmaxf(lg2, lg3));
            m = fmaxf(m, __shfl_xor(m, 1));
            m = fmaxf(m, __shfl_xor(m, 2));
            m = fmaxf(m, __shfl_xor(m, 4));
            float p0 = __expf(lg0 - m), p1 = __expf(lg1 - m);
            float p2 = __expf(lg2 - m), p3 = __expf(lg3 - m);
            float ss = p0 + p1 + p2 + p3;
            ss += __shfl_xor(ss, 1);
            ss += __shfl_xor(ss, 2);
            ss += __shfl_xor(ss, 4);
            float inv = 1.0f / ss;
            float a0 = p0 * inv, a1 = p1 * inv, a2 = p2 * inv, a3 = p3 * inv;
            al[r8][kq]      = a0;  asum[0] += a0;
            al[r8][kq + 8]  = a1;  asum[1] += a1;
            al[r8][kq + 16] = a2;  asum[2] += a2;
            al[r8][kq + 24] = a3;  asum[3] += a3;
        }
        __syncthreads();

        // ---- aggregation: vacc[k] += a[n][k] * x[n][d=t] (fp32 VALU) ----
#pragma unroll 2
        for (int n = 0; n < RG; n++) {
            float xv = bf2f(xh[(n * DD + t) ^ ((n & 7) << 3)]);
            float4 q0 = *(float4*)&al[n][0];
            float4 q1 = *(float4*)&al[n][4];
            float4 q2 = *(float4*)&al[n][8];
            float4 q3 = *(float4*)&al[n][12];
            float4 q4 = *(float4*)&al[n][16];
            float4 q5 = *(float4*)&al[n][20];
            float4 q6 = *(float4*)&al[n][24];
            float4 q7 = *(float4*)&al[n][28];
            vacc[0]  += q0.x * xv; vacc[1]  += q0.y * xv; vacc[2]  += q0.z * xv; vacc[3]  += q0.w * xv;
            vacc[4]  += q1.x * xv; vacc[5]  += q1.y * xv; vacc[6]  += q1.z * xv; vacc[7]  += q1.w * xv;
            vacc[8]  += q2.x * xv; vacc[9]  += q2.y * xv; vacc[10] += q2.z * xv; vacc[11] += q2.w * xv;
            vacc[12] += q3.x * xv; vacc[13] += q3.y * xv; vacc[14] += q3.z * xv; vacc[15] += q3.w * xv;
            vacc[16] += q4.x * xv; vacc[17] += q4.y * xv; vacc[18] += q4.z * xv; vacc[19] += q4.w * xv;
            vacc[20] += q5.x * xv; vacc[21] += q5.y * xv; vacc[22] += q5.z * xv; vacc[23] += q5.w * xv;
            vacc[24] += q6.x * xv; vacc[25] += q6.y * xv; vacc[26] += q6.z * xv; vacc[27] += q6.w * xv;
            vacc[28] += q7.x * xv; vacc[29] += q7.y * xv; vacc[30] += q7.z * xv; vacc[31] += q7.w * xv;
        }
        __syncthreads();   // protect xh/al before next stage
    }

    // ---- a_sum partial reduction via al ----
    al[r8][kq]      = asum[0];
    al[r8][kq + 8]  = asum[1];
    al[r8][kq + 16] = asum[2];
    al[r8][kq + 24] = asum[3];
    __syncthreads();
    if (t < KK) {
        float s = 0.0f;
        for (int r = 0; r < RG; r++) s += al[r][t];
        apart[((size_t)bi * CHnum + ch) * KK + t] = s;
    }

    // ---- write v partial (coalesced) ----
    float* vp = vpart + (((size_t)bi * CHnum + ch) * KK) * DD;
#pragma unroll
    for (int k = 0; k < KK; k++) vp[(size_t)k * DD + t] = vacc[k];
}

// Reduce partials, subtract a_sum * k_mean, intra-normalize, global-normalize (= /sqrt(K)).
__global__ void netvlad_k2(const float* __restrict__ vpart,
                           const float* __restrict__ apart,
                           const float* __restrict__ kmean,
                           float* __restrict__ out,
                           int CHnum) {
    const int bi = blockIdx.x / KK;
    const int k  = blockIdx.x % KK;
    const int t  = threadIdx.x;   // d

    float v = 0.0f;
    for (int ch = 0; ch < CHnum; ch++)
        v += vpart[(((size_t)bi * CHnum + ch) * KK + k) * DD + t];

    float asum = 0.0f;
    for (int ch = 0; ch < CHnum; ch++)
        asum += apart[((size_t)bi * CHnum + ch) * KK + k];

    v -= asum * kmean[(size_t)k * DD + t];

    float sq = v * v;
    sq += __shfl_xor(sq, 1);  sq += __shfl_xor(sq, 2);  sq += __shfl_xor(sq, 4);
    sq += __shfl_xor(sq, 8);  sq += __shfl_xor(sq, 16); sq += __shfl_xor(sq, 32);
    __shared__ float red[4];
    if ((t & 63) == 0) red[t >> 6] = sq;
    __syncthreads();
    float tot = red[0] + red[1] + red[2] + red[3];

    const float EPS = 1e-12f;
    float invn = 1.0f / fmaxf(sqrtf(tot), EPS);
    const float invK = 0.1767766952966369f;  // 1/sqrt(32): global norm after intra-norm
    out[((size_t)bi * KK + k) * DD + t] = v * invn * invK;
}

extern "C" void kernel_launch(void* const* d_in, const int* in_sizes, int n_in,
                              void* d_out, int out_size, void* d_ws, size_t ws_size,
                              hipStream_t stream) {
    const float* x     = (const float*)d_in[0];
    const float* W     = (const float*)d_in[1];
    const float* bias  = (const float*)d_in[2];
    const float* kmean = (const float*)d_in[3];
    float* out = (float*)d_out;
    float* ws  = (float*)d_ws;

    // Per-chunk ws need: B*K*(D+1) floats = 526,336 bytes. Prefer CH=64 (1024 blocks, 4/CU).
    int CH = 64;
    while (CH > 1 && (size_t)CH * 526336ULL > ws_size) CH >>= 1;

    float* vpart = ws;
    float* apart = ws + (size_t)BB * CH * KK * DD;

    hipLaunchKernelGGL(netvlad_k1, dim3(BB * CH), dim3(256), 0, stream,
                       x, W, bias, vpart, apart, CH);
    hipLaunchKernelGGL(netvlad_k2, dim3(BB * KK), dim3(256), 0, stream,
                       vpart, apart, kmean, out, CH);
}

// Round 3
// 150.484 us; speedup vs baseline: 1.5128x; 1.0317x over previous
//
#include <hip/hip_runtime.h>
#include <math.h>

// Problem constants
#define BB 16
#define NN 16384
#define DD 256
#define KK 32
#define RG 32            // rows per group
#define ASTRIDE 36       // f32 stride for al (logits/softmax buffer)
#define ATS 40           // ushort stride for at (a^T bf16 tile): 80B rows, 16B-aligned, 2-way banks

typedef short bf16x8 __attribute__((ext_vector_type(8)));
typedef float f32x4 __attribute__((ext_vector_type(4)));

__device__ inline ushort f2bf(float f) {
    union { float f; unsigned u; } v; v.f = f;
    unsigned r = v.u + 0x7fffu + ((v.u >> 16) & 1u);   // RNE
    return (ushort)(r >> 16);
}

// Fused kernel: stage x as bf16 in TWO LDS layouts (row-major xh for logits MFMA,
// n'-permuted transposed xt for aggregation MFMA) -> logits MFMA -> fp32 softmax
// -> aggregation MFMA with register accumulators across all groups.
// 256 threads = 4 waves, LDS ~39KB -> 4 blocks/CU.
__launch_bounds__(256, 4)
__global__ void netvlad_k1(const float* __restrict__ x,
                           const float* __restrict__ W,
                           const float* __restrict__ bias,
                           float* __restrict__ vpart,
                           float* __restrict__ apart,
                           int CHnum) {
    __shared__ ushort xh[RG * DD];      // 16KB, XOR-swizzled row-major (logits B-frags)
    __shared__ ushort xt[DD * 32];      // 16KB, transposed + n'-permuted + block-swizzled
    __shared__ float  al[RG][ASTRIDE];  // 4.6KB logits/softmax buffer
    __shared__ ushort at[KK * ATS];     // 2.5KB a^T bf16 tile
    __shared__ float  bl[KK];

    const int t    = threadIdx.x;
    const int lane = t & 63;
    const int w    = t >> 6;            // wave 0..3
    const int c4   = t & 63;            // staging lane (float4 col)
    const int bi   = blockIdx.x / CHnum;
    const int ch   = blockIdx.x % CHnum;
    const int NC   = NN / CHnum;
    const int NG   = NC / RG;

    const float* xb = x + ((size_t)bi * NN + (size_t)ch * NC) * DD;

    // logits wave tiling: kc-tile = w&1, n-tile = w>>1 (as in proven v2)
    const int kct = (w & 1) * 16;
    const int nt  = (w >> 1) * 16;
    const int lr  = lane & 15;
    const int lg4 = lane >> 4;

    // W fragments (A operand) in registers: lane holds W[kct+lr][lg4*8 + j]
    bf16x8 wf[8];
#pragma unroll
    for (int ks = 0; ks < 8; ks++) {
        const float* wp = W + (size_t)(kct + lr) * DD + ks * 32 + lg4 * 8;
        float4 w0 = *(const float4*)wp;
        float4 w1 = *(const float4*)(wp + 4);
        bf16x8 f;
        f[0] = (short)f2bf(w0.x); f[1] = (short)f2bf(w0.y);
        f[2] = (short)f2bf(w0.z); f[3] = (short)f2bf(w0.w);
        f[4] = (short)f2bf(w1.x); f[5] = (short)f2bf(w1.y);
        f[6] = (short)f2bf(w1.z); f[7] = (short)f2bf(w1.w);
        wf[ks] = f;
    }
    float cb[4];
#pragma unroll
    for (int r = 0; r < 4; r++) cb[r] = bias[kct + lg4 * 4 + r];

    // aggregation accumulators: wave w owns d-tiles {4w..4w+3}, both k-tiles.
    f32x4 acc[2][4];
#pragma unroll
    for (int kt = 0; kt < 2; kt++)
#pragma unroll
        for (int dtl = 0; dtl < 4; dtl++)
            acc[kt][dtl] = (f32x4){0.f, 0.f, 0.f, 0.f};

    float asum[4] = {0.f, 0.f, 0.f, 0.f};
    const int r8 = t >> 3;              // softmax row (0..31)
    const int kq = t & 7;               // softmax k group

    // prologue: prefetch group 0 (8 float4 per thread; row r = i*4+w, cols 4*c4..)
    float4 pf[8];
#pragma unroll
    for (int i = 0; i < 8; i++) pf[i] = ((const float4*)xb)[i * 256 + t];

    for (int g = 0; g < NG; g++) {
        // ---- stage: convert pf -> bf16; write xh (row-major swz) + xt (transposed) ----
        ushort h[8][4];
#pragma unroll
        for (int i = 0; i < 8; i++) {
            h[i][0] = f2bf(pf[i].x); h[i][1] = f2bf(pf[i].y);
            h[i][2] = f2bf(pf[i].z); h[i][3] = f2bf(pf[i].w);
        }
#pragma unroll
        for (int i = 0; i < 8; i++) {
            int r = i * 4 + w;
            int idx = (r * DD + c4 * 4) ^ ((r & 7) << 3);
            ushort4 s4; s4.x = h[i][0]; s4.y = h[i][1]; s4.z = h[i][2]; s4.w = h[i][3];
            *(ushort4*)&xh[idx] = s4;
        }
        // xt: thread holds rows n = 4j+w at d = 4c4+e  ->  n' = w*8 + j (contiguous!)
#pragma unroll
        for (int e = 0; e < 4; e++) {
            bf16x8 p;
#pragma unroll
            for (int j = 0; j < 8; j++) p[j] = (short)h[j][e];
            int d = 4 * c4 + e;
            int idx = d * 32 + ((w ^ (c4 & 3)) << 3);   // block-swizzle by (d>>2)&3 = c4&3
            *(bf16x8*)&xt[idx] = p;
        }
        if (g == 0 && t < KK) bl[t] = bias[t];
        __syncthreads();

        // ---- prefetch next group's x into registers (hidden under compute) ----
        if (g + 1 < NG) {
            const float* xn = xb + (size_t)(g + 1) * RG * DD;
#pragma unroll
            for (int i = 0; i < 8; i++) pf[i] = ((const float4*)xn)[i * 256 + t];
        }

        // ---- logits MFMA: L[kc][n] = sum_d W[kc][d] x[n][d] + b ----
        {
            f32x4 c; c[0] = cb[0]; c[1] = cb[1]; c[2] = cb[2]; c[3] = cb[3];
            const int n = nt + lr;
#pragma unroll
            for (int ks = 0; ks < 8; ks++) {
                int d0  = ks * 32 + lg4 * 8;
                int idx = (n * DD + d0) ^ ((n & 7) << 3);
                bf16x8 bfr = *(const bf16x8*)&xh[idx];
                c = __builtin_amdgcn_mfma_f32_16x16x32_bf16(wf[ks], bfr, c, 0, 0, 0);
            }
#pragma unroll
            for (int r = 0; r < 4; r++) al[n][kct + lg4 * 4 + r] = c[r];
        }
        __syncthreads();

        // ---- softmax over kc (fp32); write a^T bf16 with n' permutation ----
        {
            float lg0 = al[r8][kq], lg1 = al[r8][kq + 8];
            float lg2 = al[r8][kq + 16], lg3 = al[r8][kq + 24];
            float m = fmaxf(fmaxf(lg0, lg1), fmaxf(lg2, lg3));
            m = fmaxf(m, __shfl_xor(m, 1));
            m = fmaxf(m, __shfl_xor(m, 2));
            m = fmaxf(m, __shfl_xor(m, 4));
            float p0 = __expf(lg0 - m), p1 = __expf(lg1 - m);
            float p2 = __expf(lg2 - m), p3 = __expf(lg3 - m);
            float ss = p0 + p1 + p2 + p3;
            ss += __shfl_xor(ss, 1);
            ss += __shfl_xor(ss, 2);
            ss += __shfl_xor(ss, 4);
            float inv = 1.0f / ss;
            float a0 = p0 * inv, a1 = p1 * inv, a2 = p2 * inv, a3 = p3 * inv;
            int np = (r8 & 3) * 8 + (r8 >> 2);          // n' permutation
            at[(kq)      * ATS + np] = f2bf(a0);  asum[0] += a0;
            at[(kq + 8)  * ATS + np] = f2bf(a1);  asum[1] += a1;
            at[(kq + 16) * ATS + np] = f2bf(a2);  asum[2] += a2;
            at[(kq + 24) * ATS + np] = f2bf(a3);  asum[3] += a3;
        }
        __syncthreads();

        // ---- aggregation MFMA: acc[kt][dtl] += a^T(k×n') · x(n'×d) ----
        {
            bf16x8 af0 = *(const bf16x8*)&at[(lr)      * ATS + lg4 * 8];
            bf16x8 af1 = *(const bf16x8*)&at[(16 + lr) * ATS + lg4 * 8];
#pragma unroll
            for (int dtl = 0; dtl < 4; dtl++) {
                int d   = (w * 4 + dtl) * 16 + lr;
                int idx = d * 32 + ((lg4 ^ ((d >> 2) & 3)) << 3);
                bf16x8 bfr = *(const bf16x8*)&xt[idx];
                acc[0][dtl] = __builtin_amdgcn_mfma_f32_16x16x32_bf16(af0, bfr, acc[0][dtl], 0, 0, 0);
                acc[1][dtl] = __builtin_amdgcn_mfma_f32_16x16x32_bf16(af1, bfr, acc[1][dtl], 0, 0, 0);
            }
        }
        __syncthreads();   // protect xh/xt/at before next stage
    }

    // ---- a_sum partial reduction via al ----
    al[r8][kq]      = asum[0];
    al[r8][kq + 8]  = asum[1];
    al[r8][kq + 16] = asum[2];
    al[r8][kq + 24] = asum[3];
    __syncthreads();
    if (t < KK) {
        float s = 0.0f;
        for (int r = 0; r < RG; r++) s += al[r][t];
        apart[((size_t)bi * CHnum + ch) * KK + t] = s;
    }

    // ---- write v partial: acc[kt][dtl][r] -> v[k][d] ----
    float* vp = vpart + (((size_t)bi * CHnum + ch) * KK) * DD;
#pragma unroll
    for (int kt = 0; kt < 2; kt++)
#pragma unroll
        for (int dtl = 0; dtl < 4; dtl++) {
            int d = (w * 4 + dtl) * 16 + lr;
            int kbase = kt * 16 + lg4 * 4;
#pragma unroll
            for (int r = 0; r < 4; r++)
                vp[(size_t)(kbase + r) * DD + d] = acc[kt][dtl][r];
        }
}

// Reduce partials, subtract a_sum * k_mean, intra-normalize, global-normalize (= /sqrt(K)).
__global__ void netvlad_k2(const float* __restrict__ vpart,
                           const float* __restrict__ apart,
                           const float* __restrict__ kmean,
                           float* __restrict__ out,
                           int CHnum) {
    const int bi = blockIdx.x / KK;
    const int k  = blockIdx.x % KK;
    const int t  = threadIdx.x;   // d

    float v = 0.0f;
    for (int ch = 0; ch < CHnum; ch++)
        v += vpart[(((size_t)bi * CHnum + ch) * KK + k) * DD + t];

    float asum = 0.0f;
    for (int ch = 0; ch < CHnum; ch++)
        asum += apart[((size_t)bi * CHnum + ch) * KK + k];

    v -= asum * kmean[(size_t)k * DD + t];

    float sq = v * v;
    sq += __shfl_xor(sq, 1);  sq += __shfl_xor(sq, 2);  sq += __shfl_xor(sq, 4);
    sq += __shfl_xor(sq, 8);  sq += __shfl_xor(sq, 16); sq += __shfl_xor(sq, 32);
    __shared__ float red[4];
    if ((t & 63) == 0) red[t >> 6] = sq;
    __syncthreads();
    float tot = red[0] + red[1] + red[2] + red[3];

    const float EPS = 1e-12f;
    float invn = 1.0f / fmaxf(sqrtf(tot), EPS);
    const float invK = 0.1767766952966369f;  // 1/sqrt(32): global norm after intra-norm
    out[((size_t)bi * KK + k) * DD + t] = v * invn * invK;
}

extern "C" void kernel_launch(void* const* d_in, const int* in_sizes, int n_in,
                              void* d_out, int out_size, void* d_ws, size_t ws_size,
                              hipStream_t stream) {
    const float* x     = (const float*)d_in[0];
    const float* W     = (const float*)d_in[1];
    const float* bias  = (const float*)d_in[2];
    const float* kmean = (const float*)d_in[3];
    float* out = (float*)d_out;
    float* ws  = (float*)d_ws;

    // Per-chunk ws need: B*K*(D+1) floats = 526,336 bytes. Prefer CH=64 (1024 blocks, 4/CU).
    int CH = 64;
    while (CH > 1 && (size_t)CH * 526336ULL > ws_size) CH >>= 1;

    float* vpart = ws;
    float* apart = ws + (size_t)BB * CH * KK * DD;

    hipLaunchKernelGGL(netvlad_k1, dim3(BB * CH), dim3(256), 0, stream,
                       x, W, bias, vpart, apart, CH);
    hipLaunchKernelGGL(netvlad_k2, dim3(BB * KK), dim3(256), 0, stream,
                       vpart, apart, kmean, out, CH);
}

// Round 4
// 150.031 us; speedup vs baseline: 1.5173x; 1.0030x over previous
//
#include <hip/hip_runtime.h>
#include <math.h>

// Problem constants
#define BB 16
#define NN 16384
#define DD 256
#define KK 32
#define RG 32            // rows per group
#define ASTRIDE 36       // f32 stride for al (logits/softmax buffer)
#define ATS 40           // ushort stride for at (a^T bf16 tile)

typedef short bf16x8 __attribute__((ext_vector_type(8)));
typedef float f32x4 __attribute__((ext_vector_type(4)));

__device__ inline ushort f2bf(float f) {
    union { float f; unsigned u; } v; v.f = f;
    unsigned r = v.u + 0x7fffu + ((v.u >> 16) & 1u);   // RNE
    return (ushort)(r >> 16);
}

// Raw barrier: LDS-drain only — does NOT drain vmcnt, so global prefetch loads
// stay in flight across it (the round-3 killer was __syncthreads' vmcnt(0) drain).
#define KBAR() do {                                          \
    asm volatile("s_waitcnt lgkmcnt(0)" ::: "memory");       \
    __builtin_amdgcn_s_barrier();                            \
    __builtin_amdgcn_sched_barrier(0);                       \
} while (0)

// Fused kernel: stage x as bf16 in TWO LDS layouts -> logits MFMA -> fp32 softmax
// -> aggregation MFMA with register accumulators. Raw-barrier pipeline keeps the
// next group's global loads in flight across all 4 per-group barriers.
// 256 threads = 4 waves, LDS ~39KB -> 4 blocks/CU.
__launch_bounds__(256, 4)
__global__ void netvlad_k1(const float* __restrict__ x,
                           const float* __restrict__ W,
                           const float* __restrict__ bias,
                           float* __restrict__ vpart,
                           float* __restrict__ apart,
                           int CHnum) {
    __shared__ ushort xh[RG * DD];      // 16KB, XOR-swizzled row-major (logits B-frags)
    __shared__ ushort xt[DD * 32];      // 16KB, transposed + n'-permuted + block-swizzled
    __shared__ float  al[RG][ASTRIDE];  // 4.6KB logits buffer
    __shared__ ushort at[KK * ATS];     // 2.5KB a^T bf16 tile

    const int t    = threadIdx.x;
    const int lane = t & 63;
    const int w    = t >> 6;            // wave 0..3
    const int c4   = t & 63;            // staging lane (float4 col)
    const int bi   = blockIdx.x / CHnum;
    const int ch   = blockIdx.x % CHnum;
    const int NC   = NN / CHnum;
    const int NG   = NC / RG;

    const float* xb = x + ((size_t)bi * NN + (size_t)ch * NC) * DD;

    // logits wave tiling: kc-tile = w&1, n-tile = w>>1
    const int kct = (w & 1) * 16;
    const int nt  = (w >> 1) * 16;
    const int lr  = lane & 15;
    const int lg4 = lane >> 4;

    // W fragments (A operand) in registers: lane holds W[kct+lr][lg4*8 + j]
    bf16x8 wf[8];
#pragma unroll
    for (int ks = 0; ks < 8; ks++) {
        const float* wp = W + (size_t)(kct + lr) * DD + ks * 32 + lg4 * 8;
        float4 w0 = *(const float4*)wp;
        float4 w1 = *(const float4*)(wp + 4);
        bf16x8 f;
        f[0] = (short)f2bf(w0.x); f[1] = (short)f2bf(w0.y);
        f[2] = (short)f2bf(w0.z); f[3] = (short)f2bf(w0.w);
        f[4] = (short)f2bf(w1.x); f[5] = (short)f2bf(w1.y);
        f[6] = (short)f2bf(w1.z); f[7] = (short)f2bf(w1.w);
        wf[ks] = f;
    }
    float cb[4];
#pragma unroll
    for (int r = 0; r < 4; r++) cb[r] = bias[kct + lg4 * 4 + r];

    // aggregation accumulators: wave w owns d-tiles {4w..4w+3}, both k-tiles.
    f32x4 acc[2][4];
#pragma unroll
    for (int kt = 0; kt < 2; kt++)
#pragma unroll
        for (int dtl = 0; dtl < 4; dtl++)
            acc[kt][dtl] = (f32x4){0.f, 0.f, 0.f, 0.f};

    float asum[4] = {0.f, 0.f, 0.f, 0.f};
    const int r8 = t >> 3;              // softmax row (0..31)
    const int kq = t & 7;               // softmax k group

    // prologue: prefetch group 0 (8 float4 per thread; row r = i*4+w, cols 4*c4..)
    float4 pf[8];
#pragma unroll
    for (int i = 0; i < 8; i++) pf[i] = ((const float4*)xb)[i * 256 + t];

    for (int g = 0; g < NG; g++) {
        // ---- stage: convert pf -> bf16; write xh (row-major swz) + xt (transposed) ----
        // (compiler inserts the counted vmcnt wait for pf here — loads were issued
        //  a full group earlier and stayed in flight across the raw barriers)
        ushort h[8][4];
#pragma unroll
        for (int i = 0; i < 8; i++) {
            h[i][0] = f2bf(pf[i].x); h[i][1] = f2bf(pf[i].y);
            h[i][2] = f2bf(pf[i].z); h[i][3] = f2bf(pf[i].w);
        }
#pragma unroll
        for (int i = 0; i < 8; i++) {
            int r = i * 4 + w;
            int idx = (r * DD + c4 * 4) ^ ((r & 7) << 3);
            ushort4 s4; s4.x = h[i][0]; s4.y = h[i][1]; s4.z = h[i][2]; s4.w = h[i][3];
            *(ushort4*)&xh[idx] = s4;
        }
        // xt: thread holds rows n = 4j+w at d = 4c4+e  ->  n' = w*8 + j (contiguous)
#pragma unroll
        for (int e = 0; e < 4; e++) {
            bf16x8 p;
#pragma unroll
            for (int j = 0; j < 8; j++) p[j] = (short)h[j][e];
            int d = 4 * c4 + e;
            int idx = d * 32 + ((w ^ (c4 & 3)) << 3);   // block-swizzle by (d>>2)&3 = c4&3
            *(bf16x8*)&xt[idx] = p;
        }
        KBAR();   // xh/xt ready

        // ---- issue next group's global loads NOW; they stay in flight across
        //      the remaining barriers (no vmcnt drain) ----
        if (g + 1 < NG) {
            const float* xn = xb + (size_t)(g + 1) * RG * DD;
#pragma unroll
            for (int i = 0; i < 8; i++) pf[i] = ((const float4*)xn)[i * 256 + t];
        }
        __builtin_amdgcn_sched_barrier(0);   // pin load-issue point

        // ---- logits MFMA: L[kc][n] = sum_d W[kc][d] x[n][d] + b ----
        {
            f32x4 c; c[0] = cb[0]; c[1] = cb[1]; c[2] = cb[2]; c[3] = cb[3];
            const int n = nt + lr;
#pragma unroll
            for (int ks = 0; ks < 8; ks++) {
                int d0  = ks * 32 + lg4 * 8;
                int idx = (n * DD + d0) ^ ((n & 7) << 3);
                bf16x8 bfr = *(const bf16x8*)&xh[idx];
                c = __builtin_amdgcn_mfma_f32_16x16x32_bf16(wf[ks], bfr, c, 0, 0, 0);
            }
#pragma unroll
            for (int r = 0; r < 4; r++) al[n][kct + lg4 * 4 + r] = c[r];
        }
        KBAR();   // al ready

        // ---- softmax over kc (fp32); write a^T bf16 with n' permutation ----
        {
            float lg0 = al[r8][kq], lg1 = al[r8][kq + 8];
            float lg2 = al[r8][kq + 16], lg3 = al[r8][kq + 24];
            float m = fmaxf(fmaxf(lg0, lg1), fmaxf(lg2, lg3));
            m = fmaxf(m, __shfl_xor(m, 1));
            m = fmaxf(m, __shfl_xor(m, 2));
            m = fmaxf(m, __shfl_xor(m, 4));
            float p0 = __expf(lg0 - m), p1 = __expf(lg1 - m);
            float p2 = __expf(lg2 - m), p3 = __expf(lg3 - m);
            float ss = p0 + p1 + p2 + p3;
            ss += __shfl_xor(ss, 1);
            ss += __shfl_xor(ss, 2);
            ss += __shfl_xor(ss, 4);
            float inv = 1.0f / ss;
            float a0 = p0 * inv, a1 = p1 * inv, a2 = p2 * inv, a3 = p3 * inv;
            int np = (r8 & 3) * 8 + (r8 >> 2);          // n' permutation
            at[(kq)      * ATS + np] = f2bf(a0);  asum[0] += a0;
            at[(kq + 8)  * ATS + np] = f2bf(a1);  asum[1] += a1;
            at[(kq + 16) * ATS + np] = f2bf(a2);  asum[2] += a2;
            at[(kq + 24) * ATS + np] = f2bf(a3);  asum[3] += a3;
        }
        KBAR();   // at ready

        // ---- aggregation MFMA: acc[kt][dtl] += a^T(k×n') · x(n'×d) ----
        {
            bf16x8 af0 = *(const bf16x8*)&at[(lr)      * ATS + lg4 * 8];
            bf16x8 af1 = *(const bf16x8*)&at[(16 + lr) * ATS + lg4 * 8];
#pragma unroll
            for (int dtl = 0; dtl < 4; dtl++) {
                int d   = (w * 4 + dtl) * 16 + lr;
                int idx = d * 32 + ((lg4 ^ ((d >> 2) & 3)) << 3);
                bf16x8 bfr = *(const bf16x8*)&xt[idx];
                acc[0][dtl] = __builtin_amdgcn_mfma_f32_16x16x32_bf16(af0, bfr, acc[0][dtl], 0, 0, 0);
                acc[1][dtl] = __builtin_amdgcn_mfma_f32_16x16x32_bf16(af1, bfr, acc[1][dtl], 0, 0, 0);
            }
        }
        KBAR();   // everyone done reading xh/xt/at -> next stage may overwrite
    }

    // ---- a_sum partial reduction via al ----
    al[r8][kq]      = asum[0];
    al[r8][kq + 8]  = asum[1];
    al[r8][kq + 16] = asum[2];
    al[r8][kq + 24] = asum[3];
    __syncthreads();
    if (t < KK) {
        float s = 0.0f;
        for (int r = 0; r < RG; r++) s += al[r][t];
        apart[((size_t)bi * CHnum + ch) * KK + t] = s;
    }

    // ---- write v partial: acc[kt][dtl][r] -> v[k][d] ----
    float* vp = vpart + (((size_t)bi * CHnum + ch) * KK) * DD;
#pragma unroll
    for (int kt = 0; kt < 2; kt++)
#pragma unroll
        for (int dtl = 0; dtl < 4; dtl++) {
            int d = (w * 4 + dtl) * 16 + lr;
            int kbase = kt * 16 + lg4 * 4;
#pragma unroll
            for (int r = 0; r < 4; r++)
                vp[(size_t)(kbase + r) * DD + d] = acc[kt][dtl][r];
        }
}

// Reduce partials, subtract a_sum * k_mean, intra-normalize, global-normalize (= /sqrt(K)).
__global__ void netvlad_k2(const float* __restrict__ vpart,
                           const float* __restrict__ apart,
                           const float* __restrict__ kmean,
                           float* __restrict__ out,
                           int CHnum) {
    const int bi = blockIdx.x / KK;
    const int k  = blockIdx.x % KK;
    const int t  = threadIdx.x;   // d

    float v = 0.0f;
    for (int ch = 0; ch < CHnum; ch++)
        v += vpart[(((size_t)bi * CHnum + ch) * KK + k) * DD + t];

    float asum = 0.0f;
    for (int ch = 0; ch < CHnum; ch++)
        asum += apart[((size_t)bi * CHnum + ch) * KK + k];

    v -= asum * kmean[(size_t)k * DD + t];

    float sq = v * v;
    sq += __shfl_xor(sq, 1);  sq += __shfl_xor(sq, 2);  sq += __shfl_xor(sq, 4);
    sq += __shfl_xor(sq, 8);  sq += __shfl_xor(sq, 16); sq += __shfl_xor(sq, 32);
    __shared__ float red[4];
    if ((t & 63) == 0) red[t >> 6] = sq;
    __syncthreads();
    float tot = red[0] + red[1] + red[2] + red[3];

    const float EPS = 1e-12f;
    float invn = 1.0f / fmaxf(sqrtf(tot), EPS);
    const float invK = 0.1767766952966369f;  // 1/sqrt(32): global norm after intra-norm
    out[((size_t)bi * KK + k) * DD + t] = v * invn * invK;
}

extern "C" void kernel_launch(void* const* d_in, const int* in_sizes, int n_in,
                              void* d_out, int out_size, void* d_ws, size_t ws_size,
                              hipStream_t stream) {
    const float* x     = (const float*)d_in[0];
    const float* W     = (const float*)d_in[1];
    const float* bias  = (const float*)d_in[2];
    const float* kmean = (const float*)d_in[3];
    float* out = (float*)d_out;
    float* ws  = (float*)d_ws;

    // Per-chunk ws need: B*K*(D+1) floats = 526,336 bytes. Prefer CH=64 (1024 blocks, 4/CU).
    int CH = 64;
    while (CH > 1 && (size_t)CH * 526336ULL > ws_size) CH >>= 1;

    float* vpart = ws;
    float* apart = ws + (size_t)BB * CH * KK * DD;

    hipLaunchKernelGGL(netvlad_k1, dim3(BB * CH), dim3(256), 0, stream,
                       x, W, bias, vpart, apart, CH);
    hipLaunchKernelGGL(netvlad_k2, dim3(BB * KK), dim3(256), 0, stream,
                       vpart, apart, kmean, out, CH);
}

// Round 6
// 119.534 us; speedup vs baseline: 1.9044x; 1.2551x over previous
//
#include <hip/hip_runtime.h>
#include <hip/hip_bf16.h>
#include <math.h>

#define BB 16
#define NN 16384
#define DD 256
#define KK 32
#define RG 32            // rows per group
#define ASTRIDE 36       // f32 stride for al (logits/softmax buffer)
#define NTOT 16384       // n-columns of at_g per (b,k) row

typedef short bf16x8 __attribute__((ext_vector_type(8)));
typedef float f32x4 __attribute__((ext_vector_type(4)));

// manual RNE f32->bf16 (validated rounds 1-4)
__device__ inline ushort f2bf(float f) {
    union { float f; unsigned u; } v; v.f = f;
    unsigned r = v.u + 0x7fffu + ((v.u >> 16) & 1u);
    return (ushort)(r >> 16);
}
// packed f32x2 -> bf16x2 (RNE) via v_cvt_pk_bf16_f32
__device__ inline unsigned pk2(float lo, float hi) {
    __hip_bfloat162 h = __float22bfloat162_rn(make_float2(lo, hi));
    union { __hip_bfloat162 h; unsigned u; } v; v.h = h;
    return v.u;
}

// raw barrier: LDS-drain only; global prefetch loads stay in flight
#define KBAR()  do { asm volatile("s_waitcnt lgkmcnt(0)" ::: "memory"); \
                     __builtin_amdgcn_s_barrier();                      \
                     __builtin_amdgcn_sched_barrier(0); } while (0)

// ---------------- K_A: logits -> softmax -> a^T (bf16, n'-permuted) ----------------
// 256 thr = 4 waves; per block 256 rows (8 groups of 32). LDS 25.2KB.
__launch_bounds__(256, 4)
__global__ void netvlad_kA(const float* __restrict__ x,
                           const float* __restrict__ W,
                           const float* __restrict__ bias,
                           ushort* __restrict__ at_g,
                           float* __restrict__ apart) {
    __shared__ ushort xh[RG * DD];          // 16KB, XOR-swizzled row-major
    __shared__ float  al[2][RG][ASTRIDE];   // 9.2KB double-buffered logits

    const int t    = threadIdx.x;
    const int lane = t & 63;
    const int w    = t >> 6;
    const int c4   = t & 63;
    const int bi   = blockIdx.x >> 6;
    const int wp   = blockIdx.x & 63;

    const float* xb = x + ((size_t)bi * NN + (size_t)wp * 256) * DD;

    const int kct = (w & 1) * 16;
    const int nt  = (w >> 1) * 16;
    const int lr  = lane & 15;
    const int lg4 = lane >> 4;

    // W fragments (A operand) in registers (validated)
    bf16x8 wf[8];
#pragma unroll
    for (int ks = 0; ks < 8; ks++) {
        const float* wpt = W + (size_t)(kct + lr) * DD + ks * 32 + lg4 * 8;
        float4 w0 = *(const float4*)wpt;
        float4 w1 = *(const float4*)(wpt + 4);
        bf16x8 f;
        f[0] = (short)f2bf(w0.x); f[1] = (short)f2bf(w0.y);
        f[2] = (short)f2bf(w0.z); f[3] = (short)f2bf(w0.w);
        f[4] = (short)f2bf(w1.x); f[5] = (short)f2bf(w1.y);
        f[6] = (short)f2bf(w1.z); f[7] = (short)f2bf(w1.w);
        wf[ks] = f;
    }
    float cb[4];
#pragma unroll
    for (int r = 0; r < 4; r++) cb[r] = bias[kct + lg4 * 4 + r];

    float asum[4] = {0.f, 0.f, 0.f, 0.f};
    const int r8 = t >> 3;
    const int kq = t & 7;

    float4 pf[8];
#pragma unroll
    for (int i = 0; i < 8; i++) pf[i] = ((const float4*)xb)[i * 256 + t];

#pragma unroll 1
    for (int g = 0; g < 8; g++) {
        const int p = g & 1;
        // ---- stage xh (bf16, swizzled) ----
#pragma unroll
        for (int i = 0; i < 8; i++) {
            int r = i * 4 + w;
            unsigned lo = pk2(pf[i].x, pf[i].y);
            unsigned hi = pk2(pf[i].z, pf[i].w);
            int idx = (r * DD + c4 * 4) ^ ((r & 7) << 3);
            *(uint2*)&xh[idx] = make_uint2(lo, hi);
        }
        KBAR();   // xh ready

        // prefetch next group (stays in flight across barriers)
        if (g < 7) {
            const float* xn = xb + (size_t)(g + 1) * RG * DD;
#pragma unroll
            for (int i = 0; i < 8; i++) pf[i] = ((const float4*)xn)[i * 256 + t];
        }
        __builtin_amdgcn_sched_barrier(0);

        // ---- logits MFMA (validated): L[kc][n] ----
        {
            f32x4 c; c[0] = cb[0]; c[1] = cb[1]; c[2] = cb[2]; c[3] = cb[3];
            const int n = nt + lr;
#pragma unroll
            for (int ks = 0; ks < 8; ks++) {
                int d0  = ks * 32 + lg4 * 8;
                int idx = (n * DD + d0) ^ ((n & 7) << 3);
                bf16x8 bfr = *(const bf16x8*)&xh[idx];
                c = __builtin_amdgcn_mfma_f32_16x16x32_bf16(wf[ks], bfr, c, 0, 0, 0);
            }
#pragma unroll
            for (int r = 0; r < 4; r++) al[p][n][kct + lg4 * 4 + r] = c[r];
        }
        KBAR();   // al[p] ready; xh free for next stage

        // ---- softmax (validated) -> global a^T stores (n' permuted) ----
        {
            float lg0 = al[p][r8][kq], lg1 = al[p][r8][kq + 8];
            float lg2 = al[p][r8][kq + 16], lg3 = al[p][r8][kq + 24];
            float m = fmaxf(fmaxf(lg0, lg1), fmaxf(lg2, lg3));
            m = fmaxf(m, __shfl_xor(m, 1));
            m = fmaxf(m, __shfl_xor(m, 2));
            m = fmaxf(m, __shfl_xor(m, 4));
            float p0 = __expf(lg0 - m), p1 = __expf(lg1 - m);
            float p2 = __expf(lg2 - m), p3 = __expf(lg3 - m);
            float ss = p0 + p1 + p2 + p3;
            ss += __shfl_xor(ss, 1);
            ss += __shfl_xor(ss, 2);
            ss += __shfl_xor(ss, 4);
            float inv = 1.0f / ss;
            float a0 = p0 * inv, a1 = p1 * inv, a2 = p2 * inv, a3 = p3 * inv;
            int np = (r8 & 3) * 8 + (r8 >> 2);   // n' permutation (matches K_B's xt)
            size_t nglob = (size_t)wp * 256 + g * 32 + np;
            ushort* ap = at_g + (size_t)(bi * KK) * NTOT + nglob;
            ap[(size_t)(kq)      * NTOT] = f2bf(a0);  asum[0] += a0;
            ap[(size_t)(kq + 8)  * NTOT] = f2bf(a1);  asum[1] += a1;
            ap[(size_t)(kq + 16) * NTOT] = f2bf(a2);  asum[2] += a2;
            ap[(size_t)(kq + 24) * NTOT] = f2bf(a3);  asum[3] += a3;
        }
        // no barrier needed here: next stage writes xh (all waves passed KBAR2)
    }

    // ---- asum partial reduce via al[0] (all al reads long done) ----
    al[0][r8][kq]      = asum[0];
    al[0][r8][kq + 8]  = asum[1];
    al[0][r8][kq + 16] = asum[2];
    al[0][r8][kq + 24] = asum[3];
    __syncthreads();
    if (t < KK) {
        float s = 0.0f;
        for (int r = 0; r < RG; r++) s += al[0][r][t];
        apart[((size_t)bi * 64 + wp) * KK + t] = s;
    }
}

// ---------------- K_B: aggregation MFMA (v = a^T . x), barrier-light ----------------
// 256 thr = 4 waves; per block 256 rows; wave w owns d-tiles {4w..4w+3}, both k-halves.
__launch_bounds__(256, 4)
__global__ void netvlad_kB(const float* __restrict__ x,
                           const ushort* __restrict__ at_g,
                           float* __restrict__ vpart) {
    __shared__ ushort xt[DD * 32];   // 16KB transposed + n'-permuted + block-swizzled (round-3)

    const int t    = threadIdx.x;
    const int lane = t & 63;
    const int w    = t >> 6;
    const int c4   = t & 63;
    const int bi   = blockIdx.x >> 6;
    const int wp   = blockIdx.x & 63;
    const int l15  = lane & 15;
    const int lg4  = lane >> 4;

    const float* xb = x + ((size_t)bi * NN + (size_t)wp * 256) * DD;

    f32x4 acc[2][4];
#pragma unroll
    for (int kt = 0; kt < 2; kt++)
#pragma unroll
        for (int dtl = 0; dtl < 4; dtl++)
            acc[kt][dtl] = (f32x4){0.f, 0.f, 0.f, 0.f};

    float4 pf[8];
#pragma unroll
    for (int i = 0; i < 8; i++) pf[i] = ((const float4*)xb)[i * 256 + t];

#pragma unroll 1
    for (int g = 0; g < 8; g++) {
        // ---- issue A-frag global loads early (L3-resident at_g) ----
        const ushort* ab = at_g + (size_t)(bi * KK) * NTOT + (size_t)wp * 256 + g * 32;
        bf16x8 af0 = *(const bf16x8*)(ab + (size_t)(l15)      * NTOT + lg4 * 8);
        bf16x8 af1 = *(const bf16x8*)(ab + (size_t)(16 + l15) * NTOT + lg4 * 8);

        // ---- stage xt: register transpose via direct cvt_pk (round-3 layout) ----
        // thread holds rows n = 4i+w at d = 4*c4+e  ->  n' = w*8 + i
        {
            const float* pff = (const float*)&pf[0];   // [i*4 + e], unrolled-const idx
#pragma unroll
            for (int e = 0; e < 4; e++) {
                uint4 q;
                q.x = pk2(pff[0 * 4 + e], pff[1 * 4 + e]);
                q.y = pk2(pff[2 * 4 + e], pff[3 * 4 + e]);
                q.z = pk2(pff[4 * 4 + e], pff[5 * 4 + e]);
                q.w = pk2(pff[6 * 4 + e], pff[7 * 4 + e]);
                int d   = 4 * c4 + e;
                int idx = d * 32 + ((w ^ (c4 & 3)) << 3);
                *(uint4*)&xt[idx] = q;
            }
        }
        KBAR();   // xt ready

        // prefetch next group's x (in flight across mfma + next barrier)
        if (g < 7) {
            const float* xn = xb + (size_t)(g + 1) * RG * DD;
#pragma unroll
            for (int i = 0; i < 8; i++) pf[i] = ((const float4*)xn)[i * 256 + t];
        }
        __builtin_amdgcn_sched_barrier(0);

        // ---- aggregation MFMA (round-3 validated addressing) ----
#pragma unroll
        for (int dtl = 0; dtl < 4; dtl++) {
            int d   = (w * 4 + dtl) * 16 + l15;
            int idx = d * 32 + ((lg4 ^ ((d >> 2) & 3)) << 3);
            bf16x8 bfr = *(const bf16x8*)&xt[idx];
            acc[0][dtl] = __builtin_amdgcn_mfma_f32_16x16x32_bf16(af0, bfr, acc[0][dtl], 0, 0, 0);
            acc[1][dtl] = __builtin_amdgcn_mfma_f32_16x16x32_bf16(af1, bfr, acc[1][dtl], 0, 0, 0);
        }
        KBAR();   // all xt reads done -> next stage may overwrite
    }

    // ---- v partial stores (round-3 validated) ----
    float* vp = vpart + (((size_t)bi * 64 + wp) * KK) * DD;
#pragma unroll
    for (int kt = 0; kt < 2; kt++)
#pragma unroll
        for (int dtl = 0; dtl < 4; dtl++) {
            int d = (w * 4 + dtl) * 16 + l15;
            int kbase = kt * 16 + lg4 * 4;
#pragma unroll
            for (int r = 0; r < 4; r++)
                vp[(size_t)(kbase + r) * DD + d] = acc[kt][dtl][r];
        }
}

// ---------------- K_C: reduce + k_mean subtract + normalize ----------------
__global__ void netvlad_kC(const float* __restrict__ vpart,
                           const float* __restrict__ apart,
                           const float* __restrict__ kmean,
                           float* __restrict__ out) {
    const int bi = blockIdx.x / KK;
    const int k  = blockIdx.x % KK;
    const int t  = threadIdx.x;   // d

    float v = 0.0f;
    for (int wp = 0; wp < 64; wp++)
        v += vpart[(((size_t)bi * 64 + wp) * KK + k) * DD + t];

    float asum = 0.0f;
    for (int ch = 0; ch < 64; ch++)
        asum += apart[((size_t)bi * 64 + ch) * KK + k];

    v -= asum * kmean[(size_t)k * DD + t];

    float sq = v * v;
    sq += __shfl_xor(sq, 1);  sq += __shfl_xor(sq, 2);  sq += __shfl_xor(sq, 4);
    sq += __shfl_xor(sq, 8);  sq += __shfl_xor(sq, 16); sq += __shfl_xor(sq, 32);
    __shared__ float red[4];
    if ((t & 63) == 0) red[t >> 6] = sq;
    __syncthreads();
    float tot = red[0] + red[1] + red[2] + red[3];

    const float EPS = 1e-12f;
    float invn = 1.0f / fmaxf(sqrtf(tot), EPS);
    const float invK = 0.1767766952966369f;  // 1/sqrt(32): global norm after intra-norm
    out[((size_t)bi * KK + k) * DD + t] = v * invn * invK;
}

extern "C" void kernel_launch(void* const* d_in, const int* in_sizes, int n_in,
                              void* d_out, int out_size, void* d_ws, size_t ws_size,
                              hipStream_t stream) {
    const float* x     = (const float*)d_in[0];
    const float* W     = (const float*)d_in[1];
    const float* bias  = (const float*)d_in[2];
    const float* kmean = (const float*)d_in[3];
    float* out = (float*)d_out;

    // ws carve: vpart (33.55MB f32) | apart (128KB f32) | at_g (16.78MB bf16)
    float*  vpart = (float*)d_ws;
    float*  apart = vpart + (size_t)BB * 64 * KK * DD;
    ushort* at_g  = (ushort*)(apart + (size_t)BB * 64 * KK);

    hipLaunchKernelGGL(netvlad_kA, dim3(BB * 64), dim3(256), 0, stream,
                       x, W, bias, at_g, apart);
    hipLaunchKernelGGL(netvlad_kB, dim3(BB * 64), dim3(256), 0, stream,
                       x, at_g, vpart);
    hipLaunchKernelGGL(netvlad_kC, dim3(BB * KK), dim3(256), 0, stream,
                       vpart, apart, kmean, out);
}

// Round 7
// 116.151 us; speedup vs baseline: 1.9599x; 1.0291x over previous
//
#include <hip/hip_runtime.h>
#include <hip/hip_bf16.h>
#include <math.h>

#define BB 16
#define NN 16384
#define DD 256
#define KK 32

typedef short bf16x8 __attribute__((ext_vector_type(8)));
typedef float f32x4 __attribute__((ext_vector_type(4)));

__device__ inline unsigned pk2(float lo, float hi) {
    __hip_bfloat162 h = __float22bfloat162_rn(make_float2(lo, hi));
    union { __hip_bfloat162 h; unsigned u; } v; v.h = h;
    return v.u;
}
__device__ inline bf16x8 u4bf(uint4 q) {
    union { uint4 u; bf16x8 v; } c; c.u = q; return c.v;
}

// intra-wave LDS drain + scheduler fence (rule #18)
#define KWAIT() do { asm volatile("s_waitcnt lgkmcnt(0)" ::: "memory"); \
                     __builtin_amdgcn_sched_barrier(0); } while (0)

// compile-time float4 component select (rule #20 safe under full unroll)
#define CAE(vv, e) ((e) == 0 ? (vv).x : (e) == 1 ? (vv).y : (e) == 2 ? (vv).z : (vv).w)

// k1: 256 thr = 4 waves, each wave fully independent (ZERO block barriers in main loop).
// Wave owns 16 rows per sub-tile, 8 sub-tiles: HBM row-slice prefetch -> logits
// mfma(A=x,B=W^T) -> in-register softmax (a-frags lane-local) -> wave-private x^T
// LDS staging (L2-hit col re-read) -> deferred aggregation mfma (zero-padded K).
// LDS 48KB -> 2 blocks/CU (VGPR-bound, 8 waves/CU).
__launch_bounds__(256, 2)
__global__ void netvlad_k1(const float* __restrict__ x,
                           const float* __restrict__ W,
                           const float* __restrict__ bias,
                           float* __restrict__ vpart,
                           float* __restrict__ apart) {
    __shared__ __align__(16) char lds[49152];
    // [0,16384): Wl bf16, byte = k*512 + (dbyte ^ ((k&7)<<4))
    // [16384,49152): xt per-wave 8KB: d*32 + (nbyte ^ (((d>>3)&1)<<4))
    // epilogue: vbuf f32 [32][260] at byte 0

    const int t   = threadIdx.x;
    const int l   = t & 63;
    const int w   = t >> 6;
    const int l15 = l & 15;
    const int lg4 = l >> 4;
    const int bid = blockIdx.x;
    const int b   = bid >> 5;
    const int blk = bid & 31;

    // ---- stage Wl (bf16, swizzled) once ----
    for (int i = 0; i < 8; i++) {
        int f = i * 256 + t;             // float4 index in [0,2048)
        int k = f >> 6, c4 = f & 63;
        float4 wv = ((const float4*)W)[f];
        int byte = k * 512 + ((c4 * 8) ^ ((k & 7) << 4));
        *(uint2*)(lds + byte) = make_uint2(pk2(wv.x, wv.y), pk2(wv.z, wv.w));
    }
    const float cb0 = bias[l15];
    const float cb1 = bias[16 + l15];
    __syncthreads();                     // once; Wl read-only afterwards

    char* xtw = lds + 16384 + w * 8192;

    f32x4 acc0[16], acc1[16];
#pragma unroll
    for (int i = 0; i < 16; i++) { acc0[i] = (f32x4){0,0,0,0}; acc1[i] = (f32x4){0,0,0,0}; }
    float asr0 = 0.f, asr1 = 0.f;

    const float* xbase = x + ((size_t)b * NN + (size_t)blk * 512) * DD;

    // prologue: prefetch sub-0 row-slices: pf[2ks+h] = x[w*16+l15][ks*32+lg4*8+h*4..]
    float4 pf[16];
    {
        const float* xr = xbase + (size_t)(w * 16 + l15) * DD + lg4 * 8;
#pragma unroll
        for (int ks = 0; ks < 8; ks++) {
            pf[2 * ks]     = *(const float4*)(xr + ks * 32);
            pf[2 * ks + 1] = *(const float4*)(xr + ks * 32 + 4);
        }
    }

    uint4 af0 = make_uint4(0, 0, 0, 0), af1 = make_uint4(0, 0, 0, 0);

#pragma unroll 1
    for (int s = 0; s < 8; s++) {
        const float* xsub = xbase + ((size_t)s * 64 + (size_t)w * 16) * DD;

        // A: issue col-loads rows 0-7 (L2-hot: same 64KB the pf stream just fetched)
        float4 ca[8];
#pragma unroll
        for (int i = 0; i < 8; i++)
            ca[i] = *(const float4*)(xsub + (size_t)i * DD + l * 4);

        // B: deferred aggregation for sub s-1 (covers col-load latency)
        if (s > 0) {
            KWAIT();
#pragma unroll
            for (int dt = 0; dt < 16; dt++) {
                int d = dt * 16 + l15;
                unsigned sw = ((unsigned)(d >> 3) & 1u) << 4;
                uint2 bl = *(const uint2*)(xtw + d * 32 + ((lg4 * 8) ^ sw));
                bf16x8 bv = u4bf(make_uint4(bl.x, bl.y, 0, 0));
                acc0[dt] = __builtin_amdgcn_mfma_f32_16x16x32_bf16(u4bf(af0), bv, acc0[dt], 0, 0, 0);
                acc1[dt] = __builtin_amdgcn_mfma_f32_16x16x32_bf16(u4bf(af1), bv, acc1[dt], 0, 0, 0);
            }
        }

        // C/D: stage wave-private x^T tile (two 8-row halves, register transpose)
#pragma unroll
        for (int half = 0; half < 2; half++) {
            if (half == 1) {
#pragma unroll
                for (int i = 0; i < 8; i++)
                    ca[i] = *(const float4*)(xsub + (size_t)(8 + i) * DD + l * 4);
            }
#pragma unroll
            for (int e = 0; e < 4; e++) {
                int d = 4 * l + e;
                unsigned sw = ((unsigned)(d >> 3) & 1u) << 4;
                uint4 q;
                q.x = pk2(CAE(ca[0], e), CAE(ca[1], e));
                q.y = pk2(CAE(ca[2], e), CAE(ca[3], e));
                q.z = pk2(CAE(ca[4], e), CAE(ca[5], e));
                q.w = pk2(CAE(ca[6], e), CAE(ca[7], e));
                *(uint4*)(xtw + d * 32 + (((unsigned)(half * 16)) ^ sw)) = q;
            }
        }

        // E: logits mfma(A = x row-frags from pf, B = W^T from Wl)
        f32x4 c0 = (f32x4){cb0, cb0, cb0, cb0};
        f32x4 c1 = (f32x4){cb1, cb1, cb1, cb1};
        {
            const unsigned swk = ((unsigned)(l15 & 7)) << 4;
#pragma unroll
            for (int ks = 0; ks < 8; ks++) {
                uint4 xq;
                xq.x = pk2(pf[2 * ks].x,     pf[2 * ks].y);
                xq.y = pk2(pf[2 * ks].z,     pf[2 * ks].w);
                xq.z = pk2(pf[2 * ks + 1].x, pf[2 * ks + 1].y);
                xq.w = pk2(pf[2 * ks + 1].z, pf[2 * ks + 1].w);
                bf16x8 ax = u4bf(xq);
                bf16x8 w0 = *(const bf16x8*)(lds + l15 * 512        + (((unsigned)(ks * 64 + lg4 * 16)) ^ swk));
                bf16x8 w1 = *(const bf16x8*)(lds + (16 + l15) * 512 + (((unsigned)(ks * 64 + lg4 * 16)) ^ swk));
                c0 = __builtin_amdgcn_mfma_f32_16x16x32_bf16(ax, w0, c0, 0, 0, 0);
                c1 = __builtin_amdgcn_mfma_f32_16x16x32_bf16(ax, w1, c1, 0, 0, 0);
            }
        }

        // F: issue next sub's HBM row-slice prefetch (in flight across softmax+agg+stage)
        if (s < 7) {
            const float* xr = xbase + ((size_t)(s + 1) * 64 + (size_t)(w * 16 + l15)) * DD + lg4 * 8;
#pragma unroll
            for (int ks = 0; ks < 8; ks++) {
                pf[2 * ks]     = *(const float4*)(xr + ks * 32);
                pf[2 * ks + 1] = *(const float4*)(xr + ks * 32 + 4);
            }
        }
        __builtin_amdgcn_sched_barrier(0);

        // G: softmax over k=32 (16 lanes x 2 tiles), fully in-register
        float a0v[4], a1v[4];
#pragma unroll
        for (int r = 0; r < 4; r++) {
            float m = fmaxf(c0[r], c1[r]);
            m = fmaxf(m, __shfl_xor(m, 1));
            m = fmaxf(m, __shfl_xor(m, 2));
            m = fmaxf(m, __shfl_xor(m, 4));
            m = fmaxf(m, __shfl_xor(m, 8));
            float p0 = __expf(c0[r] - m), p1 = __expf(c1[r] - m);
            float ss = p0 + p1;
            ss += __shfl_xor(ss, 1);
            ss += __shfl_xor(ss, 2);
            ss += __shfl_xor(ss, 4);
            ss += __shfl_xor(ss, 8);
            float inv = 1.0f / ss;
            a0v[r] = p0 * inv; a1v[r] = p1 * inv;
        }
        asr0 += a0v[0] + a0v[1] + a0v[2] + a0v[3];
        asr1 += a1v[0] + a1v[1] + a1v[2] + a1v[3];
        af0 = make_uint4(pk2(a0v[0], a0v[1]), pk2(a0v[2], a0v[3]), 0, 0);
        af1 = make_uint4(pk2(a1v[0], a1v[1]), pk2(a1v[2], a1v[3]), 0, 0);
    }

    // tail aggregation for sub 7
    KWAIT();
#pragma unroll
    for (int dt = 0; dt < 16; dt++) {
        int d = dt * 16 + l15;
        unsigned sw = ((unsigned)(d >> 3) & 1u) << 4;
        uint2 bl = *(const uint2*)(xtw + d * 32 + ((lg4 * 8) ^ sw));
        bf16x8 bv = u4bf(make_uint4(bl.x, bl.y, 0, 0));
        acc0[dt] = __builtin_amdgcn_mfma_f32_16x16x32_bf16(u4bf(af0), bv, acc0[dt], 0, 0, 0);
        acc1[dt] = __builtin_amdgcn_mfma_f32_16x16x32_bf16(u4bf(af1), bv, acc1[dt], 0, 0, 0);
    }

    // ---- asum: reduce over lg4 groups; per-wave global partials ----
    asr0 += __shfl_xor(asr0, 16);  asr0 += __shfl_xor(asr0, 32);
    asr1 += __shfl_xor(asr1, 16);  asr1 += __shfl_xor(asr1, 32);
    if (l < 16) {
        float* ap = apart + ((size_t)bid * 4 + w) * KK;
        ap[l15]      = asr0;
        ap[16 + l15] = asr1;
    }

    // ---- epilogue: cross-wave v reduce via LDS (Wl/xt dead) ----
    __syncthreads();
    float* vb = (float*)lds;             // [32][260] f32
    for (int ww = 0; ww < 4; ww++) {
        if (w == ww) {
#pragma unroll
            for (int dt = 0; dt < 16; dt++) {
                int d = dt * 16 + l15;
#pragma unroll
                for (int r = 0; r < 4; r++) {
                    int k0 = lg4 * 4 + r;
                    if (ww == 0) {
                        vb[k0 * 260 + d]        = acc0[dt][r];
                        vb[(16 + k0) * 260 + d] = acc1[dt][r];
                    } else {
                        vb[k0 * 260 + d]        += acc0[dt][r];
                        vb[(16 + k0) * 260 + d] += acc1[dt][r];
                    }
                }
            }
        }
        __syncthreads();
    }
    float* vp = vpart + (size_t)bid * KK * DD;
#pragma unroll
    for (int i = 0; i < 8; i++) {
        int f = i * 256 + t;
        int k = f >> 6, c4 = f & 63;
        f32x4 v4 = *(const f32x4*)&vb[k * 260 + c4 * 4];
        *(f32x4*)&vp[(size_t)k * DD + c4 * 4] = v4;
    }
}

// kC: reduce 32 v-partials + 128 asum-partials, subtract a_sum*k_mean, normalize.
__global__ void netvlad_kC(const float* __restrict__ vpart,
                           const float* __restrict__ apart,
                           const float* __restrict__ kmean,
                           float* __restrict__ out) {
    const int bi = blockIdx.x / KK;
    const int k  = blockIdx.x % KK;
    const int t  = threadIdx.x;   // d

    float v = 0.0f;
    for (int j = 0; j < 32; j++)
        v += vpart[(((size_t)bi * 32 + j) * KK + k) * DD + t];

    float asum = 0.0f;
    for (int j = 0; j < 128; j++)
        asum += apart[((size_t)bi * 128 + j) * KK + k];

    v -= asum * kmean[(size_t)k * DD + t];

    float sq = v * v;
    sq += __shfl_xor(sq, 1);  sq += __shfl_xor(sq, 2);  sq += __shfl_xor(sq, 4);
    sq += __shfl_xor(sq, 8);  sq += __shfl_xor(sq, 16); sq += __shfl_xor(sq, 32);
    __shared__ float red[4];
    if ((t & 63) == 0) red[t >> 6] = sq;
    __syncthreads();
    float tot = red[0] + red[1] + red[2] + red[3];

    const float EPS = 1e-12f;
    float invn = 1.0f / fmaxf(sqrtf(tot), EPS);
    const float invK = 0.1767766952966369f;  // 1/sqrt(32): global norm after intra-norm
    out[((size_t)bi * KK + k) * DD + t] = v * invn * invK;
}

extern "C" void kernel_launch(void* const* d_in, const int* in_sizes, int n_in,
                              void* d_out, int out_size, void* d_ws, size_t ws_size,
                              hipStream_t stream) {
    const float* x     = (const float*)d_in[0];
    const float* W     = (const float*)d_in[1];
    const float* bias  = (const float*)d_in[2];
    const float* kmean = (const float*)d_in[3];
    float* out = (float*)d_out;

    // ws carve: vpart (512*32*256 f32 = 16.8MB) | apart (2048*32 f32 = 256KB)
    float* vpart = (float*)d_ws;
    float* apart = vpart + (size_t)512 * KK * DD;

    hipLaunchKernelGGL(netvlad_k1, dim3(512), dim3(256), 0, stream,
                       x, W, bias, vpart, apart);
    hipLaunchKernelGGL(netvlad_kC, dim3(BB * KK), dim3(256), 0, stream,
                       vpart, apart, kmean, out);
}